// Round 1
// baseline (323.419 us; speedup 1.0000x reference)
//
#include <hip/hip_runtime.h>
#include <hip/hip_bf16.h>
#include <math.h>

typedef __attribute__((ext_vector_type(8))) short short8;
typedef __attribute__((ext_vector_type(4))) float f32x4;
typedef __attribute__((ext_vector_type(4))) int int4v;

#define LOG2E 1.4426950408889634f

static __device__ __forceinline__ unsigned short f2bf(float f) {
  unsigned u = __float_as_uint(f);
  u = u + 0x7FFFu + ((u >> 16) & 1u);   // RNE
  return (unsigned short)(u >> 16);
}

// monotonic float<->uint key (no NaNs in data)
static __device__ __forceinline__ unsigned keyof(float x) {
  unsigned u = __float_as_uint(x);
  return (u & 0x80000000u) ? ~u : (u | 0x80000000u);
}
static __device__ __forceinline__ float keyinv(unsigned k) {
  unsigned u = (k & 0x80000000u) ? (k & 0x7FFFFFFFu) : ~k;
  return __uint_as_float(u);
}

// ---------------- f32 -> bf16 elementwise (8/thread) ----------------
__global__ __launch_bounds__(256) void cvt_bf16_k(const float* __restrict__ in,
                                                  unsigned short* __restrict__ out, int n8) {
  int i = blockIdx.x * blockDim.x + threadIdx.x;
  if (i >= n8) return;
  const f32x4* p = (const f32x4*)in + 2 * (size_t)i;
  f32x4 a = p[0], b = p[1];
  short8 r;
  r[0] = (short)f2bf(a[0]); r[1] = (short)f2bf(a[1]);
  r[2] = (short)f2bf(a[2]); r[3] = (short)f2bf(a[3]);
  r[4] = (short)f2bf(b[0]); r[5] = (short)f2bf(b[1]);
  r[6] = (short)f2bf(b[2]); r[7] = (short)f2bf(b[3]);
  ((short8*)out)[i] = r;
}

// ---------------- W [k][n] f32 -> Wt [n][k] bf16 (1024x1024) ----------------
__global__ __launch_bounds__(256) void wtrans_k(const float* __restrict__ W,
                                                unsigned short* __restrict__ Wt) {
  __shared__ float tile[32][33];
  const int tx = threadIdx.x, ty = threadIdx.y;
  const int x0 = blockIdx.x * 32, y0 = blockIdx.y * 32;
#pragma unroll
  for (int j = 0; j < 4; ++j)
    tile[ty + j * 8][tx] = W[(y0 + ty + j * 8) * 1024 + x0 + tx];
  __syncthreads();
#pragma unroll
  for (int j = 0; j < 4; ++j)
    Wt[(x0 + ty + j * 8) * 1024 + (y0 + tx)] = f2bf(tile[tx][ty + j * 8]);
}

// ---------------- 128x128 bf16 MFMA GEMM body ----------------
// A: [4096][1024] bf16 row-major; Bt: [1024(n)][1024(k)] bf16; bias f32[1024]
// MODE 0: out bf16 head layout [b][h][t][d]
// MODE 1: out bf16 head-T layout [b][h][d][t]
// MODE 2: out f32 row-major [m][n]
template <int MODE>
static __device__ __forceinline__ void gemm_body(unsigned short* As, unsigned short* Bs,
                                                 const unsigned short* __restrict__ A,
                                                 const unsigned short* __restrict__ Bt,
                                                 const float* __restrict__ bias,
                                                 void* __restrict__ out) {
  const int tid = threadIdx.x;
  const int lane = tid & 63, w = tid >> 6;
  const int wr = w >> 1, wc = w & 1;
  const int m0 = blockIdx.y * 128, n0 = blockIdx.x * 128;
  const int l15 = lane & 15, l4 = lane >> 4;
  f32x4 acc[4][4] = {};
  const int r0 = tid >> 2, s0 = (tid & 3) * 8;  // 16B chunk coords (row, k-seg)
  const int r1 = r0 + 64;

  for (int kt = 0; kt < 32; ++kt) {
    const int k0 = kt * 32;
    int4v ra0 = *(const int4v*)(A + (m0 + r0) * 1024 + k0 + s0);
    int4v ra1 = *(const int4v*)(A + (m0 + r1) * 1024 + k0 + s0);
    int4v rb0 = *(const int4v*)(Bt + (n0 + r0) * 1024 + k0 + s0);
    int4v rb1 = *(const int4v*)(Bt + (n0 + r1) * 1024 + k0 + s0);
    __syncthreads();
    *(int4v*)(As + r0 * 32 + s0) = ra0;
    *(int4v*)(As + r1 * 32 + s0) = ra1;
    *(int4v*)(Bs + r0 * 32 + s0) = rb0;
    *(int4v*)(Bs + r1 * 32 + s0) = rb1;
    __syncthreads();
    short8 af[4], bfr[4];
#pragma unroll
    for (int i = 0; i < 4; ++i) {
      af[i]  = *(const short8*)(As + (wr * 64 + i * 16 + l15) * 32 + l4 * 8);
      bfr[i] = *(const short8*)(Bs + (wc * 64 + i * 16 + l15) * 32 + l4 * 8);
    }
#pragma unroll
    for (int i = 0; i < 4; ++i)
#pragma unroll
      for (int j = 0; j < 4; ++j)
        acc[i][j] = __builtin_amdgcn_mfma_f32_16x16x32_bf16(af[i], bfr[j], acc[i][j], 0, 0, 0);
  }
  // epilogue
#pragma unroll
  for (int i = 0; i < 4; ++i) {
#pragma unroll
    for (int j = 0; j < 4; ++j) {
      const int n = n0 + wc * 64 + j * 16 + l15;
      const float bv = bias[n];
#pragma unroll
      for (int r = 0; r < 4; ++r) {
        const int m = m0 + wr * 64 + i * 16 + l4 * 4 + r;
        const float v = acc[i][j][r] + bv;
        if (MODE == 2) {
          ((float*)out)[m * 1024 + n] = v;
        } else {
          const int bb = m >> 10, t = m & 1023, hh = n >> 6, dd = n & 63;
          const unsigned short bfv = f2bf(v);
          if (MODE == 0)
            ((unsigned short*)out)[(((bb << 4) + hh) * 1024 + t) * 64 + dd] = bfv;
          else
            ((unsigned short*)out)[(((bb << 4) + hh) * 64 + dd) * 1024 + t] = bfv;
        }
      }
    }
  }
}

__global__ __launch_bounds__(256) void gemm_qkv_k(
    const unsigned short* qbf, const unsigned short* kbf, const unsigned short* vbf,
    const unsigned short* Wqt, const unsigned short* Wkt, const unsigned short* Wvt,
    const float* bq, const float* bk, const float* bv,
    unsigned short* Qh, unsigned short* Kh, unsigned short* Vth) {
  __shared__ unsigned short As[128 * 32], Bs[128 * 32];
  const int z = blockIdx.z;
  const unsigned short* A  = (z == 0) ? qbf : ((z == 1) ? kbf : vbf);
  const unsigned short* Bt = (z == 0) ? Wqt : ((z == 1) ? Wkt : Wvt);
  const float* bias        = (z == 0) ? bq  : ((z == 1) ? bk  : bv);
  if (z == 2) gemm_body<1>(As, Bs, A, Bt, bias, Vth);
  else        gemm_body<0>(As, Bs, A, Bt, bias, z ? Kh : Qh);
}

__global__ __launch_bounds__(256) void gemm_out_k(const unsigned short* Y,
                                                  const unsigned short* Wot,
                                                  const float* bo, float* out) {
  __shared__ unsigned short As[128 * 32], Bs[128 * 32];
  gemm_body<2>(As, Bs, Y, Wot, bo, out);
}

// ---------------- fused attention: QK^T -> exact top-64 -> softmax -> PV ----------------
// grid (64 t-blocks, 16 heads, 4 batch), 512 threads (8 waves), 64KB dynamic LDS
__global__ __launch_bounds__(512, 4) void attn_k(const unsigned short* __restrict__ Q,
                                                 const unsigned short* __restrict__ K,
                                                 const unsigned short* __restrict__ Vt,
                                                 unsigned short* __restrict__ Y) {
  extern __shared__ __align__(16) char smem[];  // S[16][1024] f32, XOR-swizzled
  const int tid = threadIdx.x, lane = tid & 63, w = tid >> 6;
  const int t0 = blockIdx.x * 16, h = blockIdx.y, b = blockIdx.z;
  const unsigned short* Qh = Q + (((b * 16 + h) * 1024) + t0) * 64;
  const unsigned short* Kh = K + (b * 16 + h) * 65536;
  const unsigned short* Vh = Vt + (b * 16 + h) * 65536;
  const int L = t0 + 16;                 // valid key length for this row block
  const int Lpad = (L + 31) & ~31;       // PV tile padding
  const int nCT = L >> 4;                // 16-wide col tiles to compute
  const int l15 = lane & 15, l4 = lane >> 4;

#define SADDR(r, c) ((((((r) << 10) + (c)) << 2)) ^ (((r) & 7) << 4))
#define SREF(r, c) (*(float*)(smem + SADDR(r, c)))

  // ---- phase 1: S = mask(QK^T * scale) ----
  const short8 aq0 = *(const short8*)(Qh + l15 * 64 + l4 * 8);
  const short8 aq1 = *(const short8*)(Qh + l15 * 64 + 32 + l4 * 8);
  for (int ct = w; ct < nCT; ct += 8) {
    const int c0 = ct * 16;
    const short8 kb0 = *(const short8*)(Kh + (c0 + l15) * 64 + l4 * 8);
    const short8 kb1 = *(const short8*)(Kh + (c0 + l15) * 64 + 32 + l4 * 8);
    f32x4 acc = {0.f, 0.f, 0.f, 0.f};
    acc = __builtin_amdgcn_mfma_f32_16x16x32_bf16(aq0, kb0, acc, 0, 0, 0);
    acc = __builtin_amdgcn_mfma_f32_16x16x32_bf16(aq1, kb1, acc, 0, 0, 0);
    const int c = c0 + l15;
#pragma unroll
    for (int r = 0; r < 4; ++r) {
      const int row = l4 * 4 + r;
      SREF(row, c) = (c <= t0 + row) ? acc[r] * 0.125f : -INFINITY;
    }
  }
  __syncthreads();

  // ---- phase 2: per-row exact top-64 threshold + softmax (normalized, in place) ----
#pragma unroll
  for (int rr = 0; rr < 2; ++rr) {
    const int r = w * 2 + rr;            // wave-uniform row
    const int Lr = t0 + r + 1;           // # valid entries in this row
    float vals[16];
#pragma unroll
    for (int i = 0; i < 16; ++i) {
      const int c = lane + (i << 6);
      vals[i] = (c < L) ? SREF(r, c) : -INFINITY;
    }
    float mx = -INFINITY;
#pragma unroll
    for (int i = 0; i < 16; ++i) mx = fmaxf(mx, vals[i]);
#pragma unroll
    for (int o = 32; o; o >>= 1) mx = fmaxf(mx, __shfl_xor(mx, o));

    float thr = -INFINITY;
    if (Lr > 64) {
      unsigned lo = 0x007FFFFFu;         // key(-inf): count >= 64 guaranteed
      unsigned hi = keyof(mx) + 1u;      // count < 64 guaranteed
      while (hi - lo > 1u) {
        const unsigned mid = lo + ((hi - lo) >> 1);
        const float tm = keyinv(mid);
        int cnt = 0;
#pragma unroll
        for (int i = 0; i < 16; ++i) cnt += (vals[i] >= tm) ? 1 : 0;
#pragma unroll
        for (int o = 32; o; o >>= 1) cnt += __shfl_xor(cnt, o);
        if (cnt >= 64) { lo = mid; if (cnt == 64) break; }
        else hi = mid;
      }
      thr = keyinv(lo);                  // exact 64th-largest (or equivalent-set threshold)
    }
    float sum = 0.f;
#pragma unroll
    for (int i = 0; i < 16; ++i) {
      const float pv = (vals[i] >= thr) ? exp2f((vals[i] - mx) * LOG2E) : 0.f;
      vals[i] = pv;
      sum += pv;
    }
#pragma unroll
    for (int o = 32; o; o >>= 1) sum += __shfl_xor(sum, o);
    const float inv = 1.f / sum;
#pragma unroll
    for (int i = 0; i < 16; ++i) {
      if (i * 64 < Lpad) {
        const int c = lane + (i << 6);
        SREF(r, c) = vals[i] * inv;      // zeros cover [Lr,Lpad) pad for PV
      }
    }
  }
  __syncthreads();

  // ---- phase 3: y = P @ V  (waves 0..3, 16 d-cols each) ----
  if (w < 4) {
    const int d0 = w * 16;
    f32x4 acc = {0.f, 0.f, 0.f, 0.f};
    const int nST = Lpad >> 5;
    for (int st = 0; st < nST; ++st) {
      const int sb = st * 32 + l4 * 8;
      const f32x4 pa0 = *(const f32x4*)&SREF(l15, sb);
      const f32x4 pa1 = *(const f32x4*)&SREF(l15, sb + 4);
      short8 paf;
      paf[0] = (short)f2bf(pa0[0]); paf[1] = (short)f2bf(pa0[1]);
      paf[2] = (short)f2bf(pa0[2]); paf[3] = (short)f2bf(pa0[3]);
      paf[4] = (short)f2bf(pa1[0]); paf[5] = (short)f2bf(pa1[1]);
      paf[6] = (short)f2bf(pa1[2]); paf[7] = (short)f2bf(pa1[3]);
      const short8 vb = *(const short8*)(Vh + (d0 + l15) * 1024 + sb);
      acc = __builtin_amdgcn_mfma_f32_16x16x32_bf16(paf, vb, acc, 0, 0, 0);
    }
    const int d = (h << 6) + d0 + l15;
#pragma unroll
    for (int r = 0; r < 4; ++r) {
      const int tg = t0 + l4 * 4 + r;
      Y[((b << 10) + tg) * 1024 + d] = f2bf(acc[r]);
    }
  }
#undef SADDR
#undef SREF
}

// ---------------- host ----------------
extern "C" void kernel_launch(void* const* d_in, const int* in_sizes, int n_in,
                              void* d_out, int out_size, void* d_ws, size_t ws_size,
                              hipStream_t stream) {
  const float* q  = (const float*)d_in[0];
  const float* k  = (const float*)d_in[1];
  const float* v  = (const float*)d_in[2];
  // d_in[3] = tgt_mask (causal tril) — computed analytically, not read
  const float* Wq = (const float*)d_in[4];
  const float* Wk = (const float*)d_in[5];
  const float* Wv = (const float*)d_in[6];
  const float* Wo = (const float*)d_in[7];
  const float* bq = (const float*)d_in[8];
  const float* bk = (const float*)d_in[9];
  const float* bv = (const float*)d_in[10];
  const float* bo = (const float*)d_in[11];

  char* ws = (char*)d_ws;
  const size_t MB = 1u << 20;
  unsigned short* qbf = (unsigned short*)(ws + 0 * MB);   // 8MB; reused as Y later
  unsigned short* kbf = (unsigned short*)(ws + 8 * MB);   // 8MB
  unsigned short* vbf = (unsigned short*)(ws + 16 * MB);  // 8MB
  unsigned short* Wqt = (unsigned short*)(ws + 24 * MB);  // 2MB
  unsigned short* Wkt = (unsigned short*)(ws + 26 * MB);  // 2MB
  unsigned short* Wvt = (unsigned short*)(ws + 28 * MB);  // 2MB
  unsigned short* Wot = (unsigned short*)(ws + 30 * MB);  // 2MB
  unsigned short* Qh  = (unsigned short*)(ws + 32 * MB);  // 8MB [b][h][t][d]
  unsigned short* Kh  = (unsigned short*)(ws + 40 * MB);  // 8MB [b][h][t][d]
  unsigned short* Vth = (unsigned short*)(ws + 48 * MB);  // 8MB [b][h][d][t]
  unsigned short* Y   = qbf;  // alias: qbf is dead after gemm_qkv_k

  cvt_bf16_k<<<2048, 256, 0, stream>>>(q, qbf, 524288);
  cvt_bf16_k<<<2048, 256, 0, stream>>>(k, kbf, 524288);
  cvt_bf16_k<<<2048, 256, 0, stream>>>(v, vbf, 524288);
  dim3 tb(32, 8);
  wtrans_k<<<dim3(32, 32), tb, 0, stream>>>(Wq, Wqt);
  wtrans_k<<<dim3(32, 32), tb, 0, stream>>>(Wk, Wkt);
  wtrans_k<<<dim3(32, 32), tb, 0, stream>>>(Wv, Wvt);
  wtrans_k<<<dim3(32, 32), tb, 0, stream>>>(Wo, Wot);
  gemm_qkv_k<<<dim3(8, 32, 3), 256, 0, stream>>>(qbf, kbf, vbf, Wqt, Wkt, Wvt,
                                                 bq, bk, bv, Qh, Kh, Vth);
  attn_k<<<dim3(64, 16, 4), 512, 65536, stream>>>(Qh, Kh, Vth, Y);
  gemm_out_k<<<dim3(8, 32), 256, 0, stream>>>(Y, Wot, bo, (float*)d_out);
}

// Round 2
// 268.101 us; speedup vs baseline: 1.2063x; 1.2063x over previous
//
#include <hip/hip_runtime.h>
#include <hip/hip_bf16.h>
#include <math.h>

typedef __attribute__((ext_vector_type(8))) short short8;
typedef __attribute__((ext_vector_type(4))) float f32x4;
typedef __attribute__((ext_vector_type(4))) int int4v;

#define LOG2E 1.4426950408889634f

static __device__ __forceinline__ unsigned short f2bf(float f) {
  unsigned u = __float_as_uint(f);
  u = u + 0x7FFFu + ((u >> 16) & 1u);   // RNE
  return (unsigned short)(u >> 16);
}

// monotonic float<->uint key (no NaNs in data)
static __device__ __forceinline__ unsigned keyof(float x) {
  unsigned u = __float_as_uint(x);
  return (u & 0x80000000u) ? ~u : (u | 0x80000000u);
}
static __device__ __forceinline__ float keyinv(unsigned k) {
  unsigned u = (k & 0x80000000u) ? (k & 0x7FFFFFFFu) : ~k;
  return __uint_as_float(u);
}

// async global->LDS, 16B per lane (m97 pattern)
static __device__ __forceinline__ void gld_lds16(const unsigned short* g, unsigned short* l) {
  __builtin_amdgcn_global_load_lds(
      (const __attribute__((address_space(1))) void*)g,
      (__attribute__((address_space(3))) void*)l, 16, 0, 0);
}

// ---------------- f32 -> bf16 elementwise (8/thread) ----------------
__global__ __launch_bounds__(256) void cvt_bf16_k(const float* __restrict__ in,
                                                  unsigned short* __restrict__ out, int n8) {
  int i = blockIdx.x * blockDim.x + threadIdx.x;
  if (i >= n8) return;
  const f32x4* p = (const f32x4*)in + 2 * (size_t)i;
  f32x4 a = p[0], b = p[1];
  short8 r;
  r[0] = (short)f2bf(a[0]); r[1] = (short)f2bf(a[1]);
  r[2] = (short)f2bf(a[2]); r[3] = (short)f2bf(a[3]);
  r[4] = (short)f2bf(b[0]); r[5] = (short)f2bf(b[1]);
  r[6] = (short)f2bf(b[2]); r[7] = (short)f2bf(b[3]);
  ((short8*)out)[i] = r;
}

// ---------------- W [k][n] f32 -> Wt [n][k] bf16 (1024x1024) ----------------
__global__ __launch_bounds__(256) void wtrans_k(const float* __restrict__ W,
                                                unsigned short* __restrict__ Wt) {
  __shared__ float tile[32][33];
  const int tx = threadIdx.x, ty = threadIdx.y;
  const int x0 = blockIdx.x * 32, y0 = blockIdx.y * 32;
#pragma unroll
  for (int j = 0; j < 4; ++j)
    tile[ty + j * 8][tx] = W[(y0 + ty + j * 8) * 1024 + x0 + tx];
  __syncthreads();
#pragma unroll
  for (int j = 0; j < 4; ++j)
    Wt[(x0 + ty + j * 8) * 1024 + (y0 + tx)] = f2bf(tile[tx][ty + j * 8]);
}

// ---------------- 128x128 bf16 MFMA GEMM body (global_load_lds staging) ----------------
// A: [4096][1024] bf16 row-major; Bt: [1024(n)][1024(k)] bf16; bias f32[1024]
// MODE 0: out bf16 head layout [b][h][t][d]
// MODE 1: out bf16 head-T layout [b][h][d][t]
// MODE 2: out f32 row-major [m][n]
template <int MODE>
static __device__ __forceinline__ void gemm_body(unsigned short* As, unsigned short* Bs,
                                                 const unsigned short* __restrict__ A,
                                                 const unsigned short* __restrict__ Bt,
                                                 const float* __restrict__ bias,
                                                 void* __restrict__ out) {
  const int tid = threadIdx.x;
  const int lane = tid & 63, w = tid >> 6;
  const int wr = w >> 1, wc = w & 1;
  const int m0 = blockIdx.y * 128, n0 = blockIdx.x * 128;
  const int l15 = lane & 15, l4 = lane >> 4;
  f32x4 acc[4][4] = {};
  const int r0 = tid >> 2, s0 = (tid & 3) * 8;  // 16B chunk coords (row, k-seg)
  const int r1 = r0 + 64;
  const unsigned short* gA0 = A + (m0 + r0) * 1024 + s0;
  const unsigned short* gA1 = A + (m0 + r1) * 1024 + s0;
  const unsigned short* gB0 = Bt + (n0 + r0) * 1024 + s0;
  const unsigned short* gB1 = Bt + (n0 + r1) * 1024 + s0;
  unsigned short* lA0 = As + r0 * 32 + s0;   // byte offset == tid*16: linear per-lane
  unsigned short* lA1 = As + r1 * 32 + s0;
  unsigned short* lB0 = Bs + r0 * 32 + s0;
  unsigned short* lB1 = Bs + r1 * 32 + s0;

  for (int kt = 0; kt < 32; ++kt) {
    const int k0 = kt * 32;
    __syncthreads();                 // previous iter's LDS reads complete
    gld_lds16(gA0 + k0, lA0);
    gld_lds16(gA1 + k0, lA1);
    gld_lds16(gB0 + k0, lB0);
    gld_lds16(gB1 + k0, lB1);
    __syncthreads();                 // compiler drains vmcnt(0) before barrier
    short8 af[4], bfr[4];
#pragma unroll
    for (int i = 0; i < 4; ++i) {
      af[i]  = *(const short8*)(As + (wr * 64 + i * 16 + l15) * 32 + l4 * 8);
      bfr[i] = *(const short8*)(Bs + (wc * 64 + i * 16 + l15) * 32 + l4 * 8);
    }
#pragma unroll
    for (int i = 0; i < 4; ++i)
#pragma unroll
      for (int j = 0; j < 4; ++j)
        acc[i][j] = __builtin_amdgcn_mfma_f32_16x16x32_bf16(af[i], bfr[j], acc[i][j], 0, 0, 0);
  }
  // epilogue
#pragma unroll
  for (int i = 0; i < 4; ++i) {
#pragma unroll
    for (int j = 0; j < 4; ++j) {
      const int n = n0 + wc * 64 + j * 16 + l15;
      const float bv = bias[n];
#pragma unroll
      for (int r = 0; r < 4; ++r) {
        const int m = m0 + wr * 64 + i * 16 + l4 * 4 + r;
        const float v = acc[i][j][r] + bv;
        if (MODE == 2) {
          ((float*)out)[m * 1024 + n] = v;
        } else {
          const int bb = m >> 10, t = m & 1023, hh = n >> 6, dd = n & 63;
          const unsigned short bfv = f2bf(v);
          if (MODE == 0)
            ((unsigned short*)out)[(((bb << 4) + hh) * 1024 + t) * 64 + dd] = bfv;
          else
            ((unsigned short*)out)[(((bb << 4) + hh) * 64 + dd) * 1024 + t] = bfv;
        }
      }
    }
  }
}

__global__ __launch_bounds__(256) void gemm_qkv_k(
    const unsigned short* qbf, const unsigned short* kbf, const unsigned short* vbf,
    const unsigned short* Wqt, const unsigned short* Wkt, const unsigned short* Wvt,
    const float* bq, const float* bk, const float* bv,
    unsigned short* Qh, unsigned short* Kh, unsigned short* Vth) {
  __shared__ unsigned short As[128 * 32], Bs[128 * 32];
  const int z = blockIdx.z;
  const unsigned short* A  = (z == 0) ? qbf : ((z == 1) ? kbf : vbf);
  const unsigned short* Bt = (z == 0) ? Wqt : ((z == 1) ? Wkt : Wvt);
  const float* bias        = (z == 0) ? bq  : ((z == 1) ? bk  : bv);
  if (z == 2) gemm_body<1>(As, Bs, A, Bt, bias, Vth);
  else        gemm_body<0>(As, Bs, A, Bt, bias, z ? Kh : Qh);
}

__global__ __launch_bounds__(256) void gemm_out_k(const unsigned short* Y,
                                                  const unsigned short* Wot,
                                                  const float* bo, float* out) {
  __shared__ unsigned short As[128 * 32], Bs[128 * 32];
  gemm_body<2>(As, Bs, Y, Wot, bo, out);
}

// ---------------- fused attention: QK^T -> exact top-64 -> softmax -> PV ----------------
// grid (64 t-blocks, 16 heads, 4 batch), 512 threads (8 waves), 64KB dynamic LDS
// S: f32 [16][1024] swizzled; P: bf16 [16][1024] aliased into the low 32KB
__global__ __launch_bounds__(512, 4) void attn_k(const unsigned short* __restrict__ Q,
                                                 const unsigned short* __restrict__ K,
                                                 const unsigned short* __restrict__ Vt,
                                                 unsigned short* __restrict__ Y) {
  extern __shared__ __align__(16) char smem[];
  const int tid = threadIdx.x, lane = tid & 63, w = tid >> 6;
  const int t0 = blockIdx.x * 16, h = blockIdx.y, b = blockIdx.z;
  const unsigned short* Qp = Q + (((b * 16 + h) * 1024) + t0) * 64;
  const unsigned short* Kh = K + (b * 16 + h) * 65536;
  const unsigned short* Vh = Vt + (b * 16 + h) * 65536;
  const int L = t0 + 16;                 // valid key length for this row block
  const int Lpad = (L + 31) & ~31;       // PV tile padding
  const int nCT = L >> 4;                // 16-wide col tiles to compute
  const int l15 = lane & 15, l4 = lane >> 4;

#define SADDR(r, c) (((((r) << 10) + (c)) << 2) ^ (((r) & 7) << 4))
#define SREF(r, c) (*(float*)(smem + SADDR(r, c)))
#define PADDR(r, c) ((((r) << 11) + ((c) << 1)) ^ (((r) & 7) << 4))

  // ---- phase 1: S = mask(QK^T * scale) ----
  const short8 aq0 = *(const short8*)(Qp + l15 * 64 + l4 * 8);
  const short8 aq1 = *(const short8*)(Qp + l15 * 64 + 32 + l4 * 8);
  for (int ct = w; ct < nCT; ct += 8) {
    const int c0 = ct * 16;
    const short8 kb0 = *(const short8*)(Kh + (c0 + l15) * 64 + l4 * 8);
    const short8 kb1 = *(const short8*)(Kh + (c0 + l15) * 64 + 32 + l4 * 8);
    f32x4 acc = {0.f, 0.f, 0.f, 0.f};
    acc = __builtin_amdgcn_mfma_f32_16x16x32_bf16(aq0, kb0, acc, 0, 0, 0);
    acc = __builtin_amdgcn_mfma_f32_16x16x32_bf16(aq1, kb1, acc, 0, 0, 0);
    const int c = c0 + l15;
#pragma unroll
    for (int r = 0; r < 4; ++r) {
      const int row = l4 * 4 + r;
      SREF(row, c) = (c <= t0 + row) ? acc[r] * 0.125f : -INFINITY;
    }
  }
  __syncthreads();

  // ---- phase 2: per-row exact top-64 threshold + softmax -> P (bf16) ----
  const int rA = w * 2, rB = rA + 1;
  const int LrA = t0 + rA + 1, LrB = t0 + rB + 1;
  float vA[16], vB[16];
#pragma unroll
  for (int i = 0; i < 16; ++i) {
    const int c = lane + (i << 6);
    vA[i] = (c < L) ? SREF(rA, c) : -INFINITY;
    vB[i] = (c < L) ? SREF(rB, c) : -INFINITY;
  }
  __syncthreads();   // all S reads done; P writes (aliased region) may begin

  // per-lane maxes
  float lmA = vA[0], lmB = vB[0];
#pragma unroll
  for (int i = 1; i < 16; ++i) { lmA = fmaxf(lmA, vA[i]); lmB = fmaxf(lmB, vB[i]); }
  // wave max + min-of-lane-max, two rows interleaved
  float mxA = lmA, mnA = lmA, mxB = lmB, mnB = lmB;
#pragma unroll
  for (int o = 32; o; o >>= 1) {
    mxA = fmaxf(mxA, __shfl_xor(mxA, o));
    mxB = fmaxf(mxB, __shfl_xor(mxB, o));
    mnA = fminf(mnA, __shfl_xor(mnA, o));
    mnB = fminf(mnB, __shfl_xor(mnB, o));
  }

  // exact 64th-largest via scalar bisection with ballot counting
  unsigned loA, hiA, loB, hiB;
  if (LrA > 64) {  // per-block uniform: t0>=64 all rows, t0<=48 none
    loA = (unsigned)__builtin_amdgcn_readfirstlane((int)keyof(mnA));  // cnt>=64 proven
    hiA = (unsigned)__builtin_amdgcn_readfirstlane((int)keyof(mxA)) + 1u;
  } else { loA = 0u; hiA = 1u; }
  if (LrB > 64) {
    loB = (unsigned)__builtin_amdgcn_readfirstlane((int)keyof(mnB));
    hiB = (unsigned)__builtin_amdgcn_readfirstlane((int)keyof(mxB)) + 1u;
  } else { loB = 0u; hiB = 1u; }

  while (true) {
    const bool dA = (hiA - loA) > 1u, dB = (hiB - loB) > 1u;
    if (!dA && !dB) break;
    if (dA) {
      const unsigned mid = loA + ((hiA - loA) >> 1);
      const float tm = keyinv(mid);
      int cnt = 0;
#pragma unroll
      for (int i = 0; i < 16; ++i) cnt += (int)__popcll(__ballot(vA[i] >= tm));
      if (cnt >= 64) { loA = mid; if (cnt == 64) hiA = mid + 1u; }
      else hiA = mid;
    }
    if (dB) {
      const unsigned mid = loB + ((hiB - loB) >> 1);
      const float tm = keyinv(mid);
      int cnt = 0;
#pragma unroll
      for (int i = 0; i < 16; ++i) cnt += (int)__popcll(__ballot(vB[i] >= tm));
      if (cnt >= 64) { loB = mid; if (cnt == 64) hiB = mid + 1u; }
      else hiB = mid;
    }
  }
  const float thrA = (LrA > 64) ? keyinv(loA) : -INFINITY;
  const float thrB = (LrB > 64) ? keyinv(loB) : -INFINITY;

  float sA = 0.f, sB = 0.f;
#pragma unroll
  for (int i = 0; i < 16; ++i) {
    const float pA = (vA[i] >= thrA) ? exp2f((vA[i] - mxA) * LOG2E) : 0.f;
    const float pB = (vB[i] >= thrB) ? exp2f((vB[i] - mxB) * LOG2E) : 0.f;
    vA[i] = pA; sA += pA;
    vB[i] = pB; sB += pB;
  }
#pragma unroll
  for (int o = 32; o; o >>= 1) {
    sA += __shfl_xor(sA, o);
    sB += __shfl_xor(sB, o);
  }
  const float invA = 1.f / sA, invB = 1.f / sB;
#pragma unroll
  for (int i = 0; i < 16; ++i) {
    if ((i << 6) < Lpad) {
      const int c = lane + (i << 6);
      *(unsigned short*)(smem + PADDR(rA, c)) = f2bf(vA[i] * invA);
      *(unsigned short*)(smem + PADDR(rB, c)) = f2bf(vB[i] * invB);
    }
  }
  __syncthreads();

  // ---- phase 3: y = P @ V  (waves 0..3, 16 d-cols each; P already bf16) ----
  if (w < 4) {
    const int d0 = w * 16;
    f32x4 acc = {0.f, 0.f, 0.f, 0.f};
    const int nST = Lpad >> 5;
    for (int st = 0; st < nST; ++st) {
      const int sb = st * 32 + l4 * 8;
      const short8 paf = *(const short8*)(smem + PADDR(l15, sb));
      const short8 vb = *(const short8*)(Vh + (d0 + l15) * 1024 + sb);
      acc = __builtin_amdgcn_mfma_f32_16x16x32_bf16(paf, vb, acc, 0, 0, 0);
    }
    const int d = (h << 6) + d0 + l15;
#pragma unroll
    for (int r = 0; r < 4; ++r) {
      const int tg = t0 + l4 * 4 + r;
      Y[((b << 10) + tg) * 1024 + d] = f2bf(acc[r]);
    }
  }
#undef SADDR
#undef SREF
#undef PADDR
}

// ---------------- host ----------------
extern "C" void kernel_launch(void* const* d_in, const int* in_sizes, int n_in,
                              void* d_out, int out_size, void* d_ws, size_t ws_size,
                              hipStream_t stream) {
  const float* q  = (const float*)d_in[0];
  const float* k  = (const float*)d_in[1];
  const float* v  = (const float*)d_in[2];
  // d_in[3] = tgt_mask (causal tril) — computed analytically, not read
  const float* Wq = (const float*)d_in[4];
  const float* Wk = (const float*)d_in[5];
  const float* Wv = (const float*)d_in[6];
  const float* Wo = (const float*)d_in[7];
  const float* bq = (const float*)d_in[8];
  const float* bk = (const float*)d_in[9];
  const float* bv = (const float*)d_in[10];
  const float* bo = (const float*)d_in[11];

  char* ws = (char*)d_ws;
  const size_t MB = 1u << 20;
  unsigned short* qbf = (unsigned short*)(ws + 0 * MB);   // 8MB; reused as Y later
  unsigned short* kbf = (unsigned short*)(ws + 8 * MB);   // 8MB
  unsigned short* vbf = (unsigned short*)(ws + 16 * MB);  // 8MB
  unsigned short* Wqt = (unsigned short*)(ws + 24 * MB);  // 2MB
  unsigned short* Wkt = (unsigned short*)(ws + 26 * MB);  // 2MB
  unsigned short* Wvt = (unsigned short*)(ws + 28 * MB);  // 2MB
  unsigned short* Wot = (unsigned short*)(ws + 30 * MB);  // 2MB
  unsigned short* Qh  = (unsigned short*)(ws + 32 * MB);  // 8MB [b][h][t][d]
  unsigned short* Kh  = (unsigned short*)(ws + 40 * MB);  // 8MB [b][h][t][d]
  unsigned short* Vth = (unsigned short*)(ws + 48 * MB);  // 8MB [b][h][d][t]
  unsigned short* Y   = qbf;  // alias: qbf is dead after gemm_qkv_k

  cvt_bf16_k<<<2048, 256, 0, stream>>>(q, qbf, 524288);
  cvt_bf16_k<<<2048, 256, 0, stream>>>(k, kbf, 524288);
  cvt_bf16_k<<<2048, 256, 0, stream>>>(v, vbf, 524288);
  dim3 tb(32, 8);
  wtrans_k<<<dim3(32, 32), tb, 0, stream>>>(Wq, Wqt);
  wtrans_k<<<dim3(32, 32), tb, 0, stream>>>(Wk, Wkt);
  wtrans_k<<<dim3(32, 32), tb, 0, stream>>>(Wv, Wvt);
  wtrans_k<<<dim3(32, 32), tb, 0, stream>>>(Wo, Wot);
  gemm_qkv_k<<<dim3(8, 32, 3), 256, 0, stream>>>(qbf, kbf, vbf, Wqt, Wkt, Wvt,
                                                 bq, bk, bv, Qh, Kh, Vth);
  attn_k<<<dim3(64, 16, 4), 512, 65536, stream>>>(Qh, Kh, Vth, Y);
  gemm_out_k<<<dim3(8, 32), 256, 0, stream>>>(Y, Wot, bo, (float*)d_out);
}

// Round 3
// 222.449 us; speedup vs baseline: 1.4539x; 1.2052x over previous
//
#include <hip/hip_runtime.h>
#include <hip/hip_bf16.h>
#include <math.h>

typedef __attribute__((ext_vector_type(8))) short short8;
typedef __attribute__((ext_vector_type(4))) float f32x4;
typedef __attribute__((ext_vector_type(4))) int int4v;

#define LOG2E 1.4426950408889634f

static __device__ __forceinline__ unsigned short f2bf(float f) {
  unsigned u = __float_as_uint(f);
  u = u + 0x7FFFu + ((u >> 16) & 1u);   // RNE
  return (unsigned short)(u >> 16);
}

// monotonic float<->uint key (no NaNs in data)
static __device__ __forceinline__ unsigned keyof(float x) {
  unsigned u = __float_as_uint(x);
  return (u & 0x80000000u) ? ~u : (u | 0x80000000u);
}
static __device__ __forceinline__ float keyinv(unsigned k) {
  unsigned u = (k & 0x80000000u) ? (k & 0x7FFFFFFFu) : ~k;
  return __uint_as_float(u);
}

// async global->LDS, 16B per lane (m97 pattern)
static __device__ __forceinline__ void gld_lds16(const unsigned short* g, unsigned short* l) {
  __builtin_amdgcn_global_load_lds(
      (const __attribute__((address_space(1))) void*)g,
      (__attribute__((address_space(3))) void*)l, 16, 0, 0);
}

// ---------------- f32 -> bf16, q/k/v fused (8/thread) ----------------
__global__ __launch_bounds__(256) void cvt3_k(const float* __restrict__ q,
                                              const float* __restrict__ k,
                                              const float* __restrict__ v,
                                              unsigned short* __restrict__ oq,
                                              unsigned short* __restrict__ ok,
                                              unsigned short* __restrict__ ov) {
  const int y = blockIdx.y;
  const float* in = (y == 0) ? q : (y == 1) ? k : v;
  unsigned short* out = (y == 0) ? oq : (y == 1) ? ok : ov;
  const int i = blockIdx.x * 256 + threadIdx.x;  // 524288 per tensor
  const f32x4* p = (const f32x4*)in + 2 * (size_t)i;
  f32x4 a = p[0], b = p[1];
  short8 r;
  r[0] = (short)f2bf(a[0]); r[1] = (short)f2bf(a[1]);
  r[2] = (short)f2bf(a[2]); r[3] = (short)f2bf(a[3]);
  r[4] = (short)f2bf(b[0]); r[5] = (short)f2bf(b[1]);
  r[6] = (short)f2bf(b[2]); r[7] = (short)f2bf(b[3]);
  ((short8*)out)[i] = r;
}

// ---------------- W [k][n] f32 -> Wt [n][k] bf16, 4 weights fused ----------------
__global__ __launch_bounds__(256) void wtrans4_k(const float* __restrict__ Wq,
                                                 const float* __restrict__ Wk,
                                                 const float* __restrict__ Wv,
                                                 const float* __restrict__ Wo,
                                                 unsigned short* __restrict__ Wqt,
                                                 unsigned short* __restrict__ Wkt,
                                                 unsigned short* __restrict__ Wvt,
                                                 unsigned short* __restrict__ Wot) {
  const int z = blockIdx.z;
  const float* W = (z == 0) ? Wq : (z == 1) ? Wk : (z == 2) ? Wv : Wo;
  unsigned short* Wt = (z == 0) ? Wqt : (z == 1) ? Wkt : (z == 2) ? Wvt : Wot;
  __shared__ float tile[32][33];
  const int tx = threadIdx.x, ty = threadIdx.y;
  const int x0 = blockIdx.x * 32, y0 = blockIdx.y * 32;
#pragma unroll
  for (int j = 0; j < 4; ++j)
    tile[ty + j * 8][tx] = W[(y0 + ty + j * 8) * 1024 + x0 + tx];
  __syncthreads();
#pragma unroll
  for (int j = 0; j < 4; ++j)
    Wt[(x0 + ty + j * 8) * 1024 + (y0 + tx)] = f2bf(tile[tx][ty + j * 8]);
}

// ---------------- 128x128 bf16 MFMA GEMM body (global_load_lds staging) ----------------
// MODE 0: out bf16 [b][h][t][d]; MODE 1: out bf16 [b][h][d][t]; MODE 2: out f32 [m][n]
template <int MODE>
static __device__ __forceinline__ void gemm_body(unsigned short* As, unsigned short* Bs,
                                                 const unsigned short* __restrict__ A,
                                                 const unsigned short* __restrict__ Bt,
                                                 const float* __restrict__ bias,
                                                 void* __restrict__ out) {
  const int tid = threadIdx.x;
  const int lane = tid & 63, w = tid >> 6;
  const int wr = w >> 1, wc = w & 1;
  const int m0 = blockIdx.y * 128, n0 = blockIdx.x * 128;
  const int l15 = lane & 15, l4 = lane >> 4;
  f32x4 acc[4][4] = {};
  const int r0 = tid >> 2, s0 = (tid & 3) * 8;
  const int r1 = r0 + 64;
  const unsigned short* gA0 = A + (m0 + r0) * 1024 + s0;
  const unsigned short* gA1 = A + (m0 + r1) * 1024 + s0;
  const unsigned short* gB0 = Bt + (n0 + r0) * 1024 + s0;
  const unsigned short* gB1 = Bt + (n0 + r1) * 1024 + s0;
  unsigned short* lA0 = As + r0 * 32 + s0;
  unsigned short* lA1 = As + r1 * 32 + s0;
  unsigned short* lB0 = Bs + r0 * 32 + s0;
  unsigned short* lB1 = Bs + r1 * 32 + s0;

  for (int kt = 0; kt < 32; ++kt) {
    const int k0 = kt * 32;
    __syncthreads();
    gld_lds16(gA0 + k0, lA0);
    gld_lds16(gA1 + k0, lA1);
    gld_lds16(gB0 + k0, lB0);
    gld_lds16(gB1 + k0, lB1);
    __syncthreads();
    short8 af[4], bfr[4];
#pragma unroll
    for (int i = 0; i < 4; ++i) {
      af[i]  = *(const short8*)(As + (wr * 64 + i * 16 + l15) * 32 + l4 * 8);
      bfr[i] = *(const short8*)(Bs + (wc * 64 + i * 16 + l15) * 32 + l4 * 8);
    }
#pragma unroll
    for (int i = 0; i < 4; ++i)
#pragma unroll
      for (int j = 0; j < 4; ++j)
        acc[i][j] = __builtin_amdgcn_mfma_f32_16x16x32_bf16(af[i], bfr[j], acc[i][j], 0, 0, 0);
  }
#pragma unroll
  for (int i = 0; i < 4; ++i) {
#pragma unroll
    for (int j = 0; j < 4; ++j) {
      const int n = n0 + wc * 64 + j * 16 + l15;
      const float bv = bias[n];
#pragma unroll
      for (int r = 0; r < 4; ++r) {
        const int m = m0 + wr * 64 + i * 16 + l4 * 4 + r;
        const float v = acc[i][j][r] + bv;
        if (MODE == 2) {
          ((float*)out)[m * 1024 + n] = v;
        } else {
          const int bb = m >> 10, t = m & 1023, hh = n >> 6, dd = n & 63;
          const unsigned short bfv = f2bf(v);
          if (MODE == 0)
            ((unsigned short*)out)[(((bb << 4) + hh) * 1024 + t) * 64 + dd] = bfv;
          else
            ((unsigned short*)out)[(((bb << 4) + hh) * 64 + dd) * 1024 + t] = bfv;
        }
      }
    }
  }
}

__global__ __launch_bounds__(256) void gemm_qkv_k(
    const unsigned short* qbf, const unsigned short* kbf, const unsigned short* vbf,
    const unsigned short* Wqt, const unsigned short* Wkt, const unsigned short* Wvt,
    const float* bq, const float* bk, const float* bv,
    unsigned short* Qh, unsigned short* Kh, unsigned short* Vth) {
  __shared__ unsigned short As[128 * 32], Bs[128 * 32];
  const int z = blockIdx.z;
  const unsigned short* A  = (z == 0) ? qbf : ((z == 1) ? kbf : vbf);
  const unsigned short* Bt = (z == 0) ? Wqt : ((z == 1) ? Wkt : Wvt);
  const float* bias        = (z == 0) ? bq  : ((z == 1) ? bk  : bv);
  if (z == 2) gemm_body<1>(As, Bs, A, Bt, bias, Vth);
  else        gemm_body<0>(As, Bs, A, Bt, bias, z ? Kh : Qh);
}

__global__ __launch_bounds__(256) void gemm_out_k(const unsigned short* Y,
                                                  const unsigned short* Wot,
                                                  const float* bo, float* out) {
  __shared__ unsigned short As[128 * 32], Bs[128 * 32];
  gemm_body<2>(As, Bs, Y, Wot, bo, out);
}

// ---------------- fused attention: QK^T -> exact top-64 -> softmax -> PV ----------------
// grid (64 t-blocks, 16 heads, 4 batch), 512 threads (8 waves), 36.25KB dynamic LDS:
//   [0,32KB):  S chunk f32[16][512] swizzled, later aliased by P bf16[16][1024]
//   [32KB,+4.25KB): phase-3 K-split partial accumulators
__global__ __launch_bounds__(512, 8) void attn_k(const unsigned short* __restrict__ Q,
                                                 const unsigned short* __restrict__ K,
                                                 const unsigned short* __restrict__ Vt,
                                                 unsigned short* __restrict__ Y) {
  extern __shared__ __align__(16) char smem[];
  const int tid = threadIdx.x, lane = tid & 63, w = tid >> 6;
  const int t0 = (63 - blockIdx.x) * 16;   // heavy blocks first
  const int h = blockIdx.y, b = blockIdx.z;
  const unsigned short* Qp = Q + (((b * 16 + h) * 1024) + t0) * 64;
  const unsigned short* Kh = K + (b * 16 + h) * 65536;
  const unsigned short* Vh = Vt + (b * 16 + h) * 65536;
  const int L = t0 + 16;
  const int Lpad = (L + 31) & ~31;
  const int nCT = L >> 4;
  const int l15 = lane & 15, l4 = lane >> 4;
  float* RED = (float*)(smem + 32768);     // [4][16][17] f32

#define SADDR(r, cc) (((((r) << 9) + (cc)) << 2) ^ (((r) & 7) << 4))
#define SREF(r, cc) (*(float*)(smem + SADDR(r, cc)))
#define PADDR(r, c) ((((r) << 11) + ((c) << 1)) ^ (((r) & 7) << 4))

  const short8 aq0 = *(const short8*)(Qp + l15 * 64 + l4 * 8);
  const short8 aq1 = *(const short8*)(Qp + l15 * 64 + 32 + l4 * 8);

  auto qk_chunk = [&](int tlo, int thi) {
    for (int ct = tlo + w; ct < thi; ct += 8) {
      const int c0 = ct * 16;
      const short8 kb0 = *(const short8*)(Kh + (c0 + l15) * 64 + l4 * 8);
      const short8 kb1 = *(const short8*)(Kh + (c0 + l15) * 64 + 32 + l4 * 8);
      f32x4 acc = {0.f, 0.f, 0.f, 0.f};
      acc = __builtin_amdgcn_mfma_f32_16x16x32_bf16(aq0, kb0, acc, 0, 0, 0);
      acc = __builtin_amdgcn_mfma_f32_16x16x32_bf16(aq1, kb1, acc, 0, 0, 0);
      const int c = c0 + l15, cc = c & 511;
#pragma unroll
      for (int r = 0; r < 4; ++r) {
        const int row = l4 * 4 + r;
        SREF(row, cc) = (c <= t0 + row) ? acc[r] * 0.125f : -INFINITY;
      }
    }
  };

  // ---- phase 1/2a: S chunk 0 (cols [0,512)) -> regs ----
  qk_chunk(0, (nCT < 32) ? nCT : 32);
  __syncthreads();
  const int rA = w * 2, rB = rA + 1;
  const int LrA = t0 + rA + 1, LrB = t0 + rB + 1;
  float vA[16], vB[16];
#pragma unroll
  for (int i = 0; i < 8; ++i) {
    const int c = lane + (i << 6);
    vA[i] = (c < L) ? SREF(rA, c) : -INFINITY;
    vB[i] = (c < L) ? SREF(rB, c) : -INFINITY;
  }
  if (L > 512) {
    __syncthreads();            // chunk-0 reads complete
    qk_chunk(32, nCT);          // S chunk 1 (cols [512,1024)) into same LDS
    __syncthreads();
#pragma unroll
    for (int i = 8; i < 16; ++i) {
      const int c = 512 + lane + ((i - 8) << 6);
      vA[i] = (c < L) ? SREF(rA, c & 511) : -INFINITY;
      vB[i] = (c < L) ? SREF(rB, c & 511) : -INFINITY;
    }
  } else {
#pragma unroll
    for (int i = 8; i < 16; ++i) { vA[i] = -INFINITY; vB[i] = -INFINITY; }
  }
  __syncthreads();              // all S reads done; P (alias) may be written

  // ---- phase 2b: exact top-64 threshold (ballot counting, interpolated pivots) ----
  float lmA = vA[0], lmB = vB[0];
#pragma unroll
  for (int i = 1; i < 16; ++i) { lmA = fmaxf(lmA, vA[i]); lmB = fmaxf(lmB, vB[i]); }
  float mxA = lmA, mnA = lmA, mxB = lmB, mnB = lmB;
#pragma unroll
  for (int o = 32; o; o >>= 1) {
    mxA = fmaxf(mxA, __shfl_xor(mxA, o));
    mxB = fmaxf(mxB, __shfl_xor(mxB, o));
    mnA = fminf(mnA, __shfl_xor(mnA, o));
    mnB = fminf(mnB, __shfl_xor(mnB, o));
  }

  unsigned loA, hiA, loB, hiB;
  int clA = LrA, chA = 0, clB = LrB, chB = 0;
  if (LrA > 64) {  // min-of-lane-maxes provably has count >= 64
    loA = (unsigned)__builtin_amdgcn_readfirstlane((int)keyof(mnA));
    hiA = (unsigned)__builtin_amdgcn_readfirstlane((int)keyof(mxA)) + 1u;
  } else { loA = 0u; hiA = 1u; }
  if (LrB > 64) {
    loB = (unsigned)__builtin_amdgcn_readfirstlane((int)keyof(mnB));
    hiB = (unsigned)__builtin_amdgcn_readfirstlane((int)keyof(mxB)) + 1u;
  } else { loB = 0u; hiB = 1u; }

  for (int it = 0; it < 64; ++it) {
    const bool dA = (hiA - loA) > 1u, dB = (hiB - loB) > 1u;
    if (!dA && !dB) break;
    if (dA) {
      const unsigned span = hiA - loA;
      unsigned off;
      if (it & 1) off = span >> 1;
      else {
        const float fr = (float)(clA - 64) / (float)(clA - chA);
        off = (unsigned)(fr * (float)span);
        if (off < 1u) off = 1u;
        if (off > span - 1u) off = span - 1u;
      }
      const unsigned mid = loA + off;
      const float tm = keyinv(mid);
      int cnt = 0;
#pragma unroll
      for (int i = 0; i < 16; ++i) cnt += (int)__popcll(__ballot(vA[i] >= tm));
      if (cnt >= 64) { loA = mid; clA = cnt; if (cnt == 64) hiA = mid + 1u; }
      else { hiA = mid; chA = cnt; }
    }
    if (dB) {
      const unsigned span = hiB - loB;
      unsigned off;
      if (it & 1) off = span >> 1;
      else {
        const float fr = (float)(clB - 64) / (float)(clB - chB);
        off = (unsigned)(fr * (float)span);
        if (off < 1u) off = 1u;
        if (off > span - 1u) off = span - 1u;
      }
      const unsigned mid = loB + off;
      const float tm = keyinv(mid);
      int cnt = 0;
#pragma unroll
      for (int i = 0; i < 16; ++i) cnt += (int)__popcll(__ballot(vB[i] >= tm));
      if (cnt >= 64) { loB = mid; clB = cnt; if (cnt == 64) hiB = mid + 1u; }
      else { hiB = mid; chB = cnt; }
    }
  }
  const float thrA = (LrA > 64) ? keyinv(loA) : -INFINITY;
  const float thrB = (LrB > 64) ? keyinv(loB) : -INFINITY;

  // ---- phase 2c: softmax -> P (bf16, aliases S) ----
  float sA = 0.f, sB = 0.f;
#pragma unroll
  for (int i = 0; i < 16; ++i) {
    const float pA = (vA[i] >= thrA) ? exp2f((vA[i] - mxA) * LOG2E) : 0.f;
    const float pB = (vB[i] >= thrB) ? exp2f((vB[i] - mxB) * LOG2E) : 0.f;
    vA[i] = pA; sA += pA;
    vB[i] = pB; sB += pB;
  }
#pragma unroll
  for (int o = 32; o; o >>= 1) {
    sA += __shfl_xor(sA, o);
    sB += __shfl_xor(sB, o);
  }
  const float invA = 1.f / sA, invB = 1.f / sB;
#pragma unroll
  for (int i = 0; i < 16; ++i) {
    if ((i << 6) < Lpad) {
      const int c = lane + (i << 6);
      *(unsigned short*)(smem + PADDR(rA, c)) = f2bf(vA[i] * invA);
      *(unsigned short*)(smem + PADDR(rB, c)) = f2bf(vB[i] * invB);
    }
  }
  __syncthreads();

  // ---- phase 3: y = P @ V, K-split over all 8 waves + LDS reduction ----
  const int nST = Lpad >> 5;
  const int stMid = (nST + 1) >> 1;
  const int d0 = (w & 3) * 16;
  const int stLo = (w < 4) ? 0 : stMid;
  const int stHi = (w < 4) ? stMid : nST;
  f32x4 acc = {0.f, 0.f, 0.f, 0.f};
  for (int st = stLo; st < stHi; ++st) {
    const int sb = st * 32 + l4 * 8;
    const short8 paf = *(const short8*)(smem + PADDR(l15, sb));
    const short8 vb = *(const short8*)(Vh + (d0 + l15) * 1024 + sb);
    acc = __builtin_amdgcn_mfma_f32_16x16x32_bf16(paf, vb, acc, 0, 0, 0);
  }
  if (w >= 4) {
    const int base = (w - 4) * 272 + l15;
#pragma unroll
    for (int r = 0; r < 4; ++r) RED[base + (l4 * 4 + r) * 17] = acc[r];
  }
  __syncthreads();
  if (w < 4) {
    const int base = w * 272 + l15;
    const int d = (h << 6) + d0 + l15;
#pragma unroll
    for (int r = 0; r < 4; ++r) {
      const float vr = acc[r] + RED[base + (l4 * 4 + r) * 17];
      const int tg = t0 + l4 * 4 + r;
      Y[((b << 10) + tg) * 1024 + d] = f2bf(vr);
    }
  }
#undef SADDR
#undef SREF
#undef PADDR
}

// ---------------- host ----------------
extern "C" void kernel_launch(void* const* d_in, const int* in_sizes, int n_in,
                              void* d_out, int out_size, void* d_ws, size_t ws_size,
                              hipStream_t stream) {
  const float* q  = (const float*)d_in[0];
  const float* k  = (const float*)d_in[1];
  const float* v  = (const float*)d_in[2];
  // d_in[3] = tgt_mask (causal tril) — computed analytically, not read
  const float* Wq = (const float*)d_in[4];
  const float* Wk = (const float*)d_in[5];
  const float* Wv = (const float*)d_in[6];
  const float* Wo = (const float*)d_in[7];
  const float* bq = (const float*)d_in[8];
  const float* bk = (const float*)d_in[9];
  const float* bv = (const float*)d_in[10];
  const float* bo = (const float*)d_in[11];

  char* ws = (char*)d_ws;
  const size_t MB = 1u << 20;
  unsigned short* qbf = (unsigned short*)(ws + 0 * MB);   // 8MB; reused as Y later
  unsigned short* kbf = (unsigned short*)(ws + 8 * MB);   // 8MB
  unsigned short* vbf = (unsigned short*)(ws + 16 * MB);  // 8MB
  unsigned short* Wqt = (unsigned short*)(ws + 24 * MB);  // 2MB
  unsigned short* Wkt = (unsigned short*)(ws + 26 * MB);  // 2MB
  unsigned short* Wvt = (unsigned short*)(ws + 28 * MB);  // 2MB
  unsigned short* Wot = (unsigned short*)(ws + 30 * MB);  // 2MB
  unsigned short* Qh  = (unsigned short*)(ws + 32 * MB);  // 8MB [b][h][t][d]
  unsigned short* Kh  = (unsigned short*)(ws + 40 * MB);  // 8MB [b][h][t][d]
  unsigned short* Vth = (unsigned short*)(ws + 48 * MB);  // 8MB [b][h][d][t]
  unsigned short* Y   = qbf;  // alias: qbf is dead after gemm_qkv_k

  cvt3_k<<<dim3(2048, 3), 256, 0, stream>>>(q, k, v, qbf, kbf, vbf);
  wtrans4_k<<<dim3(32, 32, 4), dim3(32, 8), 0, stream>>>(Wq, Wk, Wv, Wo, Wqt, Wkt, Wvt, Wot);
  gemm_qkv_k<<<dim3(8, 32, 3), 256, 0, stream>>>(qbf, kbf, vbf, Wqt, Wkt, Wvt,
                                                 bq, bk, bv, Qh, Kh, Vth);
  attn_k<<<dim3(64, 16, 4), 512, 37120, stream>>>(Qh, Kh, Vth, Y);
  gemm_out_k<<<dim3(8, 32), 256, 0, stream>>>(Y, Wot, bo, (float*)d_out);
}